// Round 13
// baseline (239.563 us; speedup 1.0000x reference)
//
#include <hip/hip_runtime.h>

// MultiHeadAttention  B=2, S=2048, DM=1024, H=16, DH=64. f32 in / f32 out.
// R13: flash drops LDS staging entirely. Evidence R7/R8/R11/R12: 45-50us
// invariant across every barrier structure -> the stall is the staged
// load->vmcnt(0)->ds_read structure itself (~2000 cyc/tile unexplained by
// pipe work). K/V fragments now load DIRECTLY to registers from the
// contiguous Ktg/Vtb tile images (16 consecutive 128B lines per b128 frag
// read, unlike R4's 96KB scatter); compiler emits fine-grained vmcnt and
// pipelines across the fully-unrolled 8-tile loop. u=4 (64 q/wave), each
// wave owns a kv QUARTER (no duplicate reads in-block); 4-way combine at
// the end through a small LDS partial buffer. No barriers in the K-loop.
// Carried: ones-MFMA denominator, swizzled Ktg/Vtb images, gemm_qkv
// coalesced epilogue, 64x128 out-proj, fused prep.

#define S_LEN 2048
#define DM 1024
#define MROWS 4096
#define QSCALE 0.1803368801111244f   // 0.125 * log2(e)

typedef unsigned short u16;
typedef unsigned int u32;
typedef __attribute__((ext_vector_type(8))) short short8;
typedef __attribute__((ext_vector_type(4))) float f32x4;
typedef __attribute__((ext_vector_type(4))) unsigned short u16x4;
typedef __attribute__((ext_vector_type(2))) unsigned int u32x2;

__device__ inline u16 f2bf(float f) {
    u32 u = __float_as_uint(f);
    u = u + 0x7fffu + ((u >> 16) & 1u);   // RNE
    return (u16)(u >> 16);
}
__device__ inline void gld_lds16(const u16* g, u16* l) {
    __builtin_amdgcn_global_load_lds(
        (const __attribute__((address_space(1))) void*)g,
        (__attribute__((address_space(3))) void*)l, 16, 0, 0);
}
__device__ inline f32x4 mfma16(short8 a, short8 b, f32x4 c) {
    return __builtin_amdgcn_mfma_f32_16x16x32_bf16(a, b, c, 0, 0, 0);
}

// ---------------- fused: x->bf16 (blocks 0..2047) + weight prep (2048..3072) --
__global__ void prep_all(const float* __restrict__ x, u16* __restrict__ xb,
                         const float* __restrict__ wq, const float* __restrict__ wk,
                         const float* __restrict__ wv, const float* __restrict__ wo,
                         const float* __restrict__ bq, const float* __restrict__ bk,
                         const float* __restrict__ bv, const float* __restrict__ bo,
                         u16* __restrict__ wallT, u16* __restrict__ woT,
                         float* __restrict__ biasAll, float* __restrict__ biasO) {
    const int t = threadIdx.x;
    if (blockIdx.x < 2048) {   // x -> bf16, 8 elems/thread
        const size_t i8 = ((size_t)blockIdx.x * 256 + t) * 8;
        const f32x4 a = ((const f32x4*)x)[i8 / 4];
        const f32x4 b = ((const f32x4*)x)[i8 / 4 + 1];
        u16 o[8];
#pragma unroll
        for (int i = 0; i < 4; i++) { o[i] = f2bf(a[i]); o[4 + i] = f2bf(b[i]); }
        *(short8*)(xb + i8) = *(const short8*)o;
        return;
    }
    const int bid = blockIdx.x - 2048;
    if (bid == 1024) {   // biases
#pragma unroll
        for (int i = 0; i < 4; i++) {
            const int idx = i * 256 + t;
            biasAll[idx]        = bq[idx] * QSCALE;
            biasAll[1024 + idx] = bk[idx];
            biasAll[2048 + idx] = bv[idx];
            biasO[idx]          = bo[idx];
        }
        return;
    }
    __shared__ float lds[64][65];
    const int m  = bid >> 8;
    const int tk = (bid >> 4) & 15;
    const int tn = bid & 15;
    const float* src = (m == 0) ? wq : (m == 1) ? wk : (m == 2) ? wv : wo;
    const float scale = (m == 0) ? QSCALE : 1.0f;
    const int r4 = t >> 6, c = t & 63;
#pragma unroll
    for (int i = 0; i < 16; i++) {
        const int k = tk * 64 + i * 4 + r4;
        lds[i * 4 + r4][c] = src[(size_t)k * 1024 + tn * 64 + c];
    }
    __syncthreads();
#pragma unroll
    for (int i = 0; i < 16; i++) {
        const int n = tn * 64 + i * 4 + r4;
        const int k = tk * 64 + c;
        const u16 v = f2bf(lds[c][i * 4 + r4] * scale);
        if (m < 3) wallT[((size_t)m * 1024 + n) * 1024 + k] = v;
        else       woT[(size_t)n * 1024 + k] = v;
    }
}

// ---------------- QKV GEMM with LDS-staged coalesced epilogue ----------------
__global__ __launch_bounds__(256, 2)
void gemm_qkv(const u16* __restrict__ A, const u16* __restrict__ Bt,
              const float* __restrict__ bias, u16* __restrict__ Cq,
              u16* __restrict__ Ck, u16* __restrict__ Cv,
              const int K, const int N) {
    __shared__ __align__(16) u16 As[128 * 32];
    __shared__ __align__(16) u16 Bs[128 * 32];
    __shared__ __align__(16) u16 Ct[128 * 136];   // 34 KB epilogue staging
    const int tid = threadIdx.x;
    const int w = tid >> 6, lane = tid & 63;
    const int wm = w >> 1, wn = w & 1;
    const int l16 = lane & 15, quad = lane >> 4;
    const int tm = blockIdx.x * 128;
    const int tn = blockIdx.y * 128;
    const int region = tn >> 10;   // 0=Q, 1=K, 2=V (uniform per block)

    const int sr = w * 16 + (lane >> 2);
    const int sc = (lane & 3) * 8;
    const u16* ag0 = A + (size_t)(tm + sr) * K + sc;
    const u16* ag1 = A + (size_t)(tm + sr + 64) * K + sc;
    const u16* bg0 = Bt + (size_t)(tn + sr) * K + sc;
    const u16* bg1 = Bt + (size_t)(tn + sr + 64) * K + sc;
    u16* al = As + w * 512;
    u16* bl = Bs + w * 512;

    f32x4 acc[4][4];
#pragma unroll
    for (int i = 0; i < 4; i++)
#pragma unroll
        for (int j = 0; j < 4; j++) acc[i][j] = (f32x4){0.f, 0.f, 0.f, 0.f};

    for (int kb = 0; kb < K; kb += 32) {
        __syncthreads();
        gld_lds16(ag0 + kb, al);
        gld_lds16(ag1 + kb, al + 2048);
        gld_lds16(bg0 + kb, bl);
        gld_lds16(bg1 + kb, bl + 2048);
        __syncthreads();
        short8 af[4], bfr[4];
#pragma unroll
        for (int i = 0; i < 4; i++) {
            af[i]  = *(const short8*)(As + (wm * 64 + i * 16 + l16) * 32 + quad * 8);
            bfr[i] = *(const short8*)(Bs + (wn * 64 + i * 16 + l16) * 32 + quad * 8);
        }
#pragma unroll
        for (int i = 0; i < 4; i++)
#pragma unroll
            for (int j = 0; j < 4; j++)
                acc[i][j] = mfma16(af[i], bfr[j], acc[i][j]);
    }

    // ---- stage C into LDS ----
    if (region < 2) {
#pragma unroll
        for (int j = 0; j < 4; j++) {
            const int colL = wn * 64 + j * 16 + l16;
            const float bv = bias[tn + colL];
#pragma unroll
            for (int i = 0; i < 4; i++) {
                const int row0 = wm * 64 + i * 16 + quad * 4;
#pragma unroll
                for (int r = 0; r < 4; r++)
                    Ct[(row0 + r) * 136 + colL] = f2bf(acc[i][j][r] + bv);
            }
        }
    } else {
#pragma unroll
        for (int j = 0; j < 4; j++) {
            const int colL = wn * 64 + j * 16 + l16;
            const float bv = bias[tn + colL];
#pragma unroll
            for (int i = 0; i < 4; i++) {
                const int row0 = wm * 64 + i * 16 + quad * 4;
                u16x4 pk;
#pragma unroll
                for (int r = 0; r < 4; r++) pk[r] = f2bf(acc[i][j][r] + bv);
                *(u16x4*)(Ct + colL * 132 + row0) = pk;
            }
        }
    }
    __syncthreads();

    // ---- coalesced b128 output ----
    if (region == 0) {
#pragma unroll
        for (int p = 0; p < 8; p++) {
            const int rowL = p * 16 + (tid >> 4);
            const int c8 = (tid & 15) * 8;
            const short8 v = *(const short8*)(Ct + rowL * 136 + c8);
            *(short8*)(Cq + (size_t)(tm + rowL) * 1024 + tn + c8) = v;
        }
    } else if (region == 1) {
        const int b = tm >> 11, sBase = tm & 2047;
#pragma unroll
        for (int p = 0; p < 8; p++) {
            const int rowL = p * 16 + (tid >> 4);
            const int c8 = (tid & 15) * 8;
            const short8 v = *(const short8*)(Ct + rowL * 136 + c8);
            const int s = sBase + rowL;
            const int hd = (tn - 1024) + c8;
            const int h = hd >> 6, dd = hd & 63;
            const int chunk = ((dd >> 3) + s) & 7;
            *(short8*)(Ck + (((size_t)(b * 16 + h) * 2048 + s) << 6) + chunk * 8) = v;
        }
    } else {
        const int b = tm >> 11, tBase = (tm & 2047) >> 6;
        const int hBase = (tn >> 6) - 32;
#pragma unroll
        for (int p = 0; p < 8; p++) {
            const int cid = p * 256 + tid;        // 0..2047
            const int q3 = cid & 7;               // phys chunk
            const int colL = (cid >> 3) & 127;
            const int half = cid >> 10;           // s-tile half
            const int d = colL & 63;
            const int h = hBase + (colL >> 6);
            const int c = (q3 - d) & 7;           // logical chunk
            const int base = (c & 3) * 4 + ((c & 4) << 3);
            const u32x2 Ar = *(const u32x2*)(Ct + colL * 132 + half * 64 + base);
            const u32x2 Br = *(const u32x2*)(Ct + colL * 132 + half * 64 + base + 16);
            union { u32 u[4]; short8 s8; } o;
            o.u[0] = __builtin_amdgcn_perm(Br[0], Ar[0], 0x05040100u);
            o.u[1] = __builtin_amdgcn_perm(Br[0], Ar[0], 0x07060302u);
            o.u[2] = __builtin_amdgcn_perm(Br[1], Ar[1], 0x05040100u);
            o.u[3] = __builtin_amdgcn_perm(Br[1], Ar[1], 0x07060302u);
            *(short8*)(Cv + (((size_t)((b * 16 + h) * 32 + tBase + half)) << 12) +
                       d * 64 + q3 * 8) = o.s8;
        }
    }
}

// ---------------- out-proj GEMM: 64x128 tile, f32 out ----------------
__global__ __launch_bounds__(256, 2)
void gemm_out64(const u16* __restrict__ A, const u16* __restrict__ Bt,
                const float* __restrict__ bias, float* __restrict__ C,
                const int K, const int N) {
    __shared__ __align__(16) u16 As[64 * 32];
    __shared__ __align__(16) u16 Bs[128 * 32];
    const int tid = threadIdx.x;
    const int w = tid >> 6, lane = tid & 63;
    const int wm = w >> 1, wn = w & 1;
    const int l16 = lane & 15, quad = lane >> 4;
    const int tm = blockIdx.x * 64;
    const int tn = blockIdx.y * 128;

    const int sr = w * 16 + (lane >> 2);
    const int sc = (lane & 3) * 8;
    const u16* ag  = A + (size_t)(tm + sr) * K + sc;
    const u16* bg0 = Bt + (size_t)(tn + sr) * K + sc;
    const u16* bg1 = Bt + (size_t)(tn + sr + 64) * K + sc;
    u16* al = As + w * 512;
    u16* bl = Bs + w * 512;

    f32x4 acc[2][4];
#pragma unroll
    for (int i = 0; i < 2; i++)
#pragma unroll
        for (int j = 0; j < 4; j++) acc[i][j] = (f32x4){0.f, 0.f, 0.f, 0.f};

    for (int kb = 0; kb < K; kb += 32) {
        __syncthreads();
        gld_lds16(ag + kb, al);
        gld_lds16(bg0 + kb, bl);
        gld_lds16(bg1 + kb, bl + 2048);
        __syncthreads();
        short8 af[2], bfr[4];
#pragma unroll
        for (int i = 0; i < 2; i++)
            af[i] = *(const short8*)(As + (wm * 32 + i * 16 + l16) * 32 + quad * 8);
#pragma unroll
        for (int j = 0; j < 4; j++)
            bfr[j] = *(const short8*)(Bs + (wn * 64 + j * 16 + l16) * 32 + quad * 8);
#pragma unroll
        for (int i = 0; i < 2; i++)
#pragma unroll
            for (int j = 0; j < 4; j++)
                acc[i][j] = mfma16(af[i], bfr[j], acc[i][j]);
    }
#pragma unroll
    for (int j = 0; j < 4; j++) {
        const int col = tn + wn * 64 + j * 16 + l16;
        const float bv = bias[col];
#pragma unroll
        for (int i = 0; i < 2; i++) {
            const int row0 = tm + wm * 32 + i * 16 + quad * 4;
#pragma unroll
            for (int r = 0; r < 4; r++)
                C[(size_t)(row0 + r) * N + col] = acc[i][j][r] + bv;
        }
    }
}

// ---------------- flash attention: register-direct K/V, no staging ----------
// Block: 4 waves, 64 q rows shared (u=4, 16 each x l16). Wave w owns kv
// quarter w (512 kv = 8 tiles of 64). Fragments load straight from the
// contiguous Ktg/Vtb tile images; no LDS, no barriers in the loop.
// 4-way combine at the end (waves 1-3 -> LDS partials, wave 0 reduces).
__global__ __launch_bounds__(256, 2)
void flash_attn(const u16* __restrict__ Qb, const u16* __restrict__ Ktg,
                const u16* __restrict__ Vtb, u16* __restrict__ O) {
    __shared__ f32x4 PB[3][16][64];       // partials from waves 1..3 (48 KB)
    __shared__ float OS[3][4][16];
    const int tid = threadIdx.x;
    const int w = tid >> 6, lane = tid & 63;
    const int l16 = lane & 15, quad = lane >> 4;
    const int bh = blockIdx.y, b = bh >> 4, h = bh & 15;
    const int q0 = blockIdx.x * 64;

    short8 qf[4][2];
#pragma unroll
    for (int u = 0; u < 4; u++) {
        const size_t qrow = (size_t)(b * S_LEN + q0 + u * 16 + l16) * 1024 + h * 64;
        qf[u][0] = *(const short8*)(Qb + qrow + quad * 8);
        qf[u][1] = *(const short8*)(Qb + qrow + 32 + quad * 8);
    }
    u16 ones_s[8];
#pragma unroll
    for (int i = 0; i < 8; i++) ones_s[i] = 0x3F80u;   // bf16 1.0
    const short8 ones = *(const short8*)ones_s;

    // wave's kv quarter base (tile images are contiguous 8 KB per 64-kv tile)
    const u16* kq = Ktg + ((size_t)bh << 17) + ((size_t)w << 15);
    const u16* vq = Vtb + ((size_t)bh << 17) + ((size_t)w << 15);
    const int ka0 = l16 * 64 + ((quad + l16) & 7) * 8;       // logical chunks 0-3
    const int ka1 = l16 * 64 + ((4 + quad + l16) & 7) * 8;   // logical chunks 4-7

    f32x4 o[4][4], osum[4];
#pragma unroll
    for (int u = 0; u < 4; u++) {
        osum[u] = (f32x4){0.f, 0.f, 0.f, 0.f};
#pragma unroll
        for (int d = 0; d < 4; d++) o[u][d] = (f32x4){0.f, 0.f, 0.f, 0.f};
    }
    const f32x4 zz = (f32x4){0.f, 0.f, 0.f, 0.f};

#pragma unroll
    for (int t = 0; t < 8; t++) {
        const u16* kt = kq + t * 4096;
        const u16* vt = vq + t * 4096;
        short8 kf[4][2], vf[4][2];
#pragma unroll
        for (int a = 0; a < 4; a++) {
            kf[a][0] = *(const short8*)(kt + a * 1024 + ka0);
            kf[a][1] = *(const short8*)(kt + a * 1024 + ka1);
        }
#pragma unroll
        for (int dv = 0; dv < 4; dv++) {
            vf[dv][0] = *(const short8*)(vt + dv * 1024 + ka0);
            vf[dv][1] = *(const short8*)(vt + dv * 1024 + ka1);
        }
        f32x4 s[4][4];
#pragma unroll
        for (int a = 0; a < 4; a++) {
#pragma unroll
            for (int u = 0; u < 4; u++) {
                s[u][a] = mfma16(kf[a][0], qf[u][0], zz);
                s[u][a] = mfma16(kf[a][1], qf[u][1], s[u][a]);
            }
        }
        union { u32 u[4]; short8 s8; } pu[4][2];
#pragma unroll
        for (int u = 0; u < 4; u++) {
#pragma unroll
            for (int r = 0; r < 4; r++) {
                const float e0 = __builtin_amdgcn_exp2f(s[u][0][r]);
                const float e1 = __builtin_amdgcn_exp2f(s[u][1][r]);
                const float e2 = __builtin_amdgcn_exp2f(s[u][2][r]);
                const float e3 = __builtin_amdgcn_exp2f(s[u][3][r]);
                pu[u][0].u[r] = __builtin_amdgcn_perm(
                    __float_as_uint(e1), __float_as_uint(e0), 0x07060302u);
                pu[u][1].u[r] = __builtin_amdgcn_perm(
                    __float_as_uint(e3), __float_as_uint(e2), 0x07060302u);
            }
            osum[u] = mfma16(ones, pu[u][0].s8, osum[u]);
            osum[u] = mfma16(ones, pu[u][1].s8, osum[u]);
        }
#pragma unroll
        for (int dv = 0; dv < 4; dv++) {
#pragma unroll
            for (int u = 0; u < 4; u++) {
                o[u][dv] = mfma16(vf[dv][0], pu[u][0].s8, o[u][dv]);
                o[u][dv] = mfma16(vf[dv][1], pu[u][1].s8, o[u][dv]);
            }
        }
    }

    // ---- 4-way combine ----
    if (w > 0) {
#pragma unroll
        for (int u = 0; u < 4; u++) {
#pragma unroll
            for (int dv = 0; dv < 4; dv++)
                PB[w - 1][u * 4 + dv][lane] = o[u][dv];
            if (quad == 0) OS[w - 1][u][l16] = osum[u][0];
        }
    }
    __syncthreads();
    if (w == 0) {
#pragma unroll
        for (int u = 0; u < 4; u++) {
            const float den = osum[u][0] + OS[0][u][l16] + OS[1][u][l16] +
                              OS[2][u][l16];
            const float inv = 1.0f / den;
            const size_t obase =
                (size_t)(b * S_LEN + q0 + u * 16 + l16) * DM + h * 64 + quad * 4;
#pragma unroll
            for (int dv = 0; dv < 4; dv++) {
                const f32x4 p0 = PB[0][u * 4 + dv][lane];
                const f32x4 p1 = PB[1][u * 4 + dv][lane];
                const f32x4 p2 = PB[2][u * 4 + dv][lane];
                u16x4 pk;
#pragma unroll
                for (int r = 0; r < 4; r++)
                    pk[r] = f2bf((o[u][dv][r] + p0[r] + p1[r] + p2[r]) * inv);
                *(u16x4*)(O + obase + dv * 16) = pk;
            }
        }
    }
}

// ---------------- launch ----------------
extern "C" void kernel_launch(void* const* d_in, const int* in_sizes, int n_in,
                              void* d_out, int out_size, void* d_ws, size_t ws_size,
                              hipStream_t stream) {
    const float* x  = (const float*)d_in[0];
    const float* wq = (const float*)d_in[1];
    const float* bq = (const float*)d_in[2];
    const float* wk = (const float*)d_in[3];
    const float* bk = (const float*)d_in[4];
    const float* wv = (const float*)d_in[5];
    const float* bv = (const float*)d_in[6];
    const float* wo = (const float*)d_in[7];
    const float* bo = (const float*)d_in[8];

    char* ws = (char*)d_ws;
    u16*   wallT   = (u16*)(ws + 64);          // 6 MB
    u16*   woT     = (u16*)(ws + 6291520);     // 2 MB
    float* biasAll = (float*)(ws + 8388672);
    float* biasO   = (float*)(ws + 8400960);
    u16*   xb      = (u16*)(ws + 8405056);     // 8 MB
    u16*   Qb      = (u16*)(ws + 16793664);    // 8 MB
    u16*   Ktg     = (u16*)(ws + 25182272);    // 8 MB (swizzled LDS image)
    u16*   Vtb     = (u16*)(ws + 33570880);    // 8 MB (swizzled LDS image)
    u16*   Obuf    = (u16*)(ws + 41959488);    // 8 MB -> ends 50,348,096

    prep_all<<<3073, 256, 0, stream>>>(x, xb, wq, wk, wv, wo, bq, bk, bv, bo,
                                       wallT, woT, biasAll, biasO);
    gemm_qkv<<<dim3(32, 24), 256, 0, stream>>>(xb, wallT, biasAll,
                                               Qb, Ktg, Vtb, 1024, 3072);
    flash_attn<<<dim3(64, 32), 256, 0, stream>>>(Qb, Ktg, Vtb, Obuf);
    gemm_out64<<<dim3(64, 8), 256, 0, stream>>>(Obuf, woT, biasO,
                                                (float*)d_out, 1024, 1024);
}

// Round 14
// 178.947 us; speedup vs baseline: 1.3387x; 1.3387x over previous
//
#include <hip/hip_runtime.h>

// MultiHeadAttention  B=2, S=2048, DM=1024, H=16, DH=64. f32 in / f32 out.
// R14: revert flash to the R10 champion (41.9us measured; R11/R12/R13
// alternatives all neutral-or-worse -> staged-shared LDS + 2-barrier is the
// plateau for this kernel). New change: gemm_qkv __launch_bounds__(256,3)
// -> 3 blocks/CU (LDS 50KB*3=150<160KB), grid 768 = 256*3 = exactly one
// residency pass (was 1.5 passes at 2/CU with a half-empty tail).
// Carried: ones-MFMA denominator flash, swizzled Ktg/Vtb images, gemm_qkv
// coalesced epilogue, 64x128 out-proj, fused prep.

#define S_LEN 2048
#define DM 1024
#define MROWS 4096
#define QSCALE 0.1803368801111244f   // 0.125 * log2(e)

typedef unsigned short u16;
typedef unsigned int u32;
typedef __attribute__((ext_vector_type(8))) short short8;
typedef __attribute__((ext_vector_type(4))) float f32x4;
typedef __attribute__((ext_vector_type(4))) unsigned short u16x4;
typedef __attribute__((ext_vector_type(2))) unsigned int u32x2;

__device__ inline u16 f2bf(float f) {
    u32 u = __float_as_uint(f);
    u = u + 0x7fffu + ((u >> 16) & 1u);   // RNE
    return (u16)(u >> 16);
}
__device__ inline void gld_lds16(const u16* g, u16* l) {
    __builtin_amdgcn_global_load_lds(
        (const __attribute__((address_space(1))) void*)g,
        (__attribute__((address_space(3))) void*)l, 16, 0, 0);
}
__device__ inline f32x4 mfma16(short8 a, short8 b, f32x4 c) {
    return __builtin_amdgcn_mfma_f32_16x16x32_bf16(a, b, c, 0, 0, 0);
}

// ---------------- fused: x->bf16 (blocks 0..2047) + weight prep (2048..3072) --
__global__ void prep_all(const float* __restrict__ x, u16* __restrict__ xb,
                         const float* __restrict__ wq, const float* __restrict__ wk,
                         const float* __restrict__ wv, const float* __restrict__ wo,
                         const float* __restrict__ bq, const float* __restrict__ bk,
                         const float* __restrict__ bv, const float* __restrict__ bo,
                         u16* __restrict__ wallT, u16* __restrict__ woT,
                         float* __restrict__ biasAll, float* __restrict__ biasO) {
    const int t = threadIdx.x;
    if (blockIdx.x < 2048) {   // x -> bf16, 8 elems/thread
        const size_t i8 = ((size_t)blockIdx.x * 256 + t) * 8;
        const f32x4 a = ((const f32x4*)x)[i8 / 4];
        const f32x4 b = ((const f32x4*)x)[i8 / 4 + 1];
        u16 o[8];
#pragma unroll
        for (int i = 0; i < 4; i++) { o[i] = f2bf(a[i]); o[4 + i] = f2bf(b[i]); }
        *(short8*)(xb + i8) = *(const short8*)o;
        return;
    }
    const int bid = blockIdx.x - 2048;
    if (bid == 1024) {   // biases
#pragma unroll
        for (int i = 0; i < 4; i++) {
            const int idx = i * 256 + t;
            biasAll[idx]        = bq[idx] * QSCALE;
            biasAll[1024 + idx] = bk[idx];
            biasAll[2048 + idx] = bv[idx];
            biasO[idx]          = bo[idx];
        }
        return;
    }
    __shared__ float lds[64][65];
    const int m  = bid >> 8;
    const int tk = (bid >> 4) & 15;
    const int tn = bid & 15;
    const float* src = (m == 0) ? wq : (m == 1) ? wk : (m == 2) ? wv : wo;
    const float scale = (m == 0) ? QSCALE : 1.0f;
    const int r4 = t >> 6, c = t & 63;
#pragma unroll
    for (int i = 0; i < 16; i++) {
        const int k = tk * 64 + i * 4 + r4;
        lds[i * 4 + r4][c] = src[(size_t)k * 1024 + tn * 64 + c];
    }
    __syncthreads();
#pragma unroll
    for (int i = 0; i < 16; i++) {
        const int n = tn * 64 + i * 4 + r4;
        const int k = tk * 64 + c;
        const u16 v = f2bf(lds[c][i * 4 + r4] * scale);
        if (m < 3) wallT[((size_t)m * 1024 + n) * 1024 + k] = v;
        else       woT[(size_t)n * 1024 + k] = v;
    }
}

// ---------------- QKV GEMM with LDS-staged coalesced epilogue ----------------
// 3 blocks/CU: grid 768 = 256 CUs x 3 -> single residency pass, no tail.
__global__ __launch_bounds__(256, 3)
void gemm_qkv(const u16* __restrict__ A, const u16* __restrict__ Bt,
              const float* __restrict__ bias, u16* __restrict__ Cq,
              u16* __restrict__ Ck, u16* __restrict__ Cv,
              const int K, const int N) {
    __shared__ __align__(16) u16 As[128 * 32];
    __shared__ __align__(16) u16 Bs[128 * 32];
    __shared__ __align__(16) u16 Ct[128 * 136];   // 34 KB epilogue staging
    const int tid = threadIdx.x;
    const int w = tid >> 6, lane = tid & 63;
    const int wm = w >> 1, wn = w & 1;
    const int l16 = lane & 15, quad = lane >> 4;
    const int tm = blockIdx.x * 128;
    const int tn = blockIdx.y * 128;
    const int region = tn >> 10;   // 0=Q, 1=K, 2=V (uniform per block)

    const int sr = w * 16 + (lane >> 2);
    const int sc = (lane & 3) * 8;
    const u16* ag0 = A + (size_t)(tm + sr) * K + sc;
    const u16* ag1 = A + (size_t)(tm + sr + 64) * K + sc;
    const u16* bg0 = Bt + (size_t)(tn + sr) * K + sc;
    const u16* bg1 = Bt + (size_t)(tn + sr + 64) * K + sc;
    u16* al = As + w * 512;
    u16* bl = Bs + w * 512;

    f32x4 acc[4][4];
#pragma unroll
    for (int i = 0; i < 4; i++)
#pragma unroll
        for (int j = 0; j < 4; j++) acc[i][j] = (f32x4){0.f, 0.f, 0.f, 0.f};

    for (int kb = 0; kb < K; kb += 32) {
        __syncthreads();
        gld_lds16(ag0 + kb, al);
        gld_lds16(ag1 + kb, al + 2048);
        gld_lds16(bg0 + kb, bl);
        gld_lds16(bg1 + kb, bl + 2048);
        __syncthreads();
        short8 af[4], bfr[4];
#pragma unroll
        for (int i = 0; i < 4; i++) {
            af[i]  = *(const short8*)(As + (wm * 64 + i * 16 + l16) * 32 + quad * 8);
            bfr[i] = *(const short8*)(Bs + (wn * 64 + i * 16 + l16) * 32 + quad * 8);
        }
#pragma unroll
        for (int i = 0; i < 4; i++)
#pragma unroll
            for (int j = 0; j < 4; j++)
                acc[i][j] = mfma16(af[i], bfr[j], acc[i][j]);
    }

    // ---- stage C into LDS ----
    if (region < 2) {
#pragma unroll
        for (int j = 0; j < 4; j++) {
            const int colL = wn * 64 + j * 16 + l16;
            const float bv = bias[tn + colL];
#pragma unroll
            for (int i = 0; i < 4; i++) {
                const int row0 = wm * 64 + i * 16 + quad * 4;
#pragma unroll
                for (int r = 0; r < 4; r++)
                    Ct[(row0 + r) * 136 + colL] = f2bf(acc[i][j][r] + bv);
            }
        }
    } else {
#pragma unroll
        for (int j = 0; j < 4; j++) {
            const int colL = wn * 64 + j * 16 + l16;
            const float bv = bias[tn + colL];
#pragma unroll
            for (int i = 0; i < 4; i++) {
                const int row0 = wm * 64 + i * 16 + quad * 4;
                u16x4 pk;
#pragma unroll
                for (int r = 0; r < 4; r++) pk[r] = f2bf(acc[i][j][r] + bv);
                *(u16x4*)(Ct + colL * 132 + row0) = pk;
            }
        }
    }
    __syncthreads();

    // ---- coalesced b128 output ----
    if (region == 0) {
#pragma unroll
        for (int p = 0; p < 8; p++) {
            const int rowL = p * 16 + (tid >> 4);
            const int c8 = (tid & 15) * 8;
            const short8 v = *(const short8*)(Ct + rowL * 136 + c8);
            *(short8*)(Cq + (size_t)(tm + rowL) * 1024 + tn + c8) = v;
        }
    } else if (region == 1) {
        const int b = tm >> 11, sBase = tm & 2047;
#pragma unroll
        for (int p = 0; p < 8; p++) {
            const int rowL = p * 16 + (tid >> 4);
            const int c8 = (tid & 15) * 8;
            const short8 v = *(const short8*)(Ct + rowL * 136 + c8);
            const int s = sBase + rowL;
            const int hd = (tn - 1024) + c8;
            const int h = hd >> 6, dd = hd & 63;
            const int chunk = ((dd >> 3) + s) & 7;
            *(short8*)(Ck + (((size_t)(b * 16 + h) * 2048 + s) << 6) + chunk * 8) = v;
        }
    } else {
        const int b = tm >> 11, tBase = (tm & 2047) >> 6;
        const int hBase = (tn >> 6) - 32;
#pragma unroll
        for (int p = 0; p < 8; p++) {
            const int cid = p * 256 + tid;        // 0..2047
            const int q3 = cid & 7;               // phys chunk
            const int colL = (cid >> 3) & 127;
            const int half = cid >> 10;           // s-tile half
            const int d = colL & 63;
            const int h = hBase + (colL >> 6);
            const int c = (q3 - d) & 7;           // logical chunk
            const int base = (c & 3) * 4 + ((c & 4) << 3);
            const u32x2 Ar = *(const u32x2*)(Ct + colL * 132 + half * 64 + base);
            const u32x2 Br = *(const u32x2*)(Ct + colL * 132 + half * 64 + base + 16);
            union { u32 u[4]; short8 s8; } o;
            o.u[0] = __builtin_amdgcn_perm(Br[0], Ar[0], 0x05040100u);
            o.u[1] = __builtin_amdgcn_perm(Br[0], Ar[0], 0x07060302u);
            o.u[2] = __builtin_amdgcn_perm(Br[1], Ar[1], 0x05040100u);
            o.u[3] = __builtin_amdgcn_perm(Br[1], Ar[1], 0x07060302u);
            *(short8*)(Cv + (((size_t)((b * 16 + h) * 32 + tBase + half)) << 12) +
                       d * 64 + q3 * 8) = o.s8;
        }
    }
}

// ---------------- out-proj GEMM: 64x128 tile, f32 out ----------------
__global__ __launch_bounds__(256, 2)
void gemm_out64(const u16* __restrict__ A, const u16* __restrict__ Bt,
                const float* __restrict__ bias, float* __restrict__ C,
                const int K, const int N) {
    __shared__ __align__(16) u16 As[64 * 32];
    __shared__ __align__(16) u16 Bs[128 * 32];
    const int tid = threadIdx.x;
    const int w = tid >> 6, lane = tid & 63;
    const int wm = w >> 1, wn = w & 1;
    const int l16 = lane & 15, quad = lane >> 4;
    const int tm = blockIdx.x * 64;
    const int tn = blockIdx.y * 128;

    const int sr = w * 16 + (lane >> 2);
    const int sc = (lane & 3) * 8;
    const u16* ag  = A + (size_t)(tm + sr) * K + sc;
    const u16* bg0 = Bt + (size_t)(tn + sr) * K + sc;
    const u16* bg1 = Bt + (size_t)(tn + sr + 64) * K + sc;
    u16* al = As + w * 512;
    u16* bl = Bs + w * 512;

    f32x4 acc[2][4];
#pragma unroll
    for (int i = 0; i < 2; i++)
#pragma unroll
        for (int j = 0; j < 4; j++) acc[i][j] = (f32x4){0.f, 0.f, 0.f, 0.f};

    for (int kb = 0; kb < K; kb += 32) {
        __syncthreads();
        gld_lds16(ag + kb, al);
        gld_lds16(bg0 + kb, bl);
        gld_lds16(bg1 + kb, bl + 2048);
        __syncthreads();
        short8 af[2], bfr[4];
#pragma unroll
        for (int i = 0; i < 2; i++)
            af[i] = *(const short8*)(As + (wm * 32 + i * 16 + l16) * 32 + quad * 8);
#pragma unroll
        for (int j = 0; j < 4; j++)
            bfr[j] = *(const short8*)(Bs + (wn * 64 + j * 16 + l16) * 32 + quad * 8);
#pragma unroll
        for (int i = 0; i < 2; i++)
#pragma unroll
            for (int j = 0; j < 4; j++)
                acc[i][j] = mfma16(af[i], bfr[j], acc[i][j]);
    }
#pragma unroll
    for (int j = 0; j < 4; j++) {
        const int col = tn + wn * 64 + j * 16 + l16;
        const float bv = bias[col];
#pragma unroll
        for (int i = 0; i < 2; i++) {
            const int row0 = tm + wm * 32 + i * 16 + quad * 4;
#pragma unroll
            for (int r = 0; r < 4; r++)
                C[(size_t)(row0 + r) * N + col] = acc[i][j][r] + bv;
        }
    }
}

// ---------------- flash attention (R10 champion config) ----------------
// Block: 4 waves x 32 q = 128 q rows; grid (16,32) = 512 blocks (2/CU).
// kv tile 64, 16 KB staged via 16x global_load_lds (4/wave), 2-barrier.
// Ones-MFMA softmax denominator (no cross-lane reduce in/after the loop).
__global__ __launch_bounds__(256, 2)
void flash_attn(const u16* __restrict__ Qb, const u16* __restrict__ Ktg,
                const u16* __restrict__ Vtb, u16* __restrict__ O) {
    __shared__ __align__(16) u16 Ks[4096];
    __shared__ __align__(16) u16 Vs[4096];
    const int tid = threadIdx.x;
    const int w = tid >> 6, lane = tid & 63;
    const int l16 = lane & 15, quad = lane >> 4;
    const int bh = blockIdx.y, b = bh >> 4, h = bh & 15;
    const int q0 = blockIdx.x * 128 + w * 32;

    short8 qf[2][2];
#pragma unroll
    for (int u = 0; u < 2; u++) {
        const size_t qrow = (size_t)(b * S_LEN + q0 + u * 16 + l16) * 1024 + h * 64;
        qf[u][0] = *(const short8*)(Qb + qrow + quad * 8);
        qf[u][1] = *(const short8*)(Qb + qrow + 32 + quad * 8);
    }
    u16 ones_s[8];
#pragma unroll
    for (int i = 0; i < 8; i++) ones_s[i] = 0x3F80u;   // bf16 1.0
    const short8 ones = *(const short8*)ones_s;

    const u16* kg = Ktg + ((size_t)bh << 17) + w * 1024 + lane * 8;
    const u16* vg = Vtb + ((size_t)bh << 17) + w * 1024 + lane * 8;
    u16* kl = Ks + w * 1024;   // wave-uniform LDS base (+ lane*16B implicit)
    u16* vl = Vs + w * 1024;

    const int ka0 = l16 * 64 + ((quad + l16) & 7) * 8;       // logical chunks 0-3
    const int ka1 = l16 * 64 + ((4 + quad + l16) & 7) * 8;   // logical chunks 4-7

    f32x4 o[2][4], osum[2];
#pragma unroll
    for (int u = 0; u < 2; u++) {
        osum[u] = (f32x4){0.f, 0.f, 0.f, 0.f};
#pragma unroll
        for (int d = 0; d < 4; d++) o[u][d] = (f32x4){0.f, 0.f, 0.f, 0.f};
    }
    const f32x4 zz = (f32x4){0.f, 0.f, 0.f, 0.f};

    for (int t = 0; t < S_LEN / 64; t++) {
        __syncthreads();
        const int off = t * 4096;
        gld_lds16(kg + off,       kl);
        gld_lds16(kg + off + 512, kl + 512);
        gld_lds16(vg + off,       vl);
        gld_lds16(vg + off + 512, vl + 512);
        __syncthreads();   // drains vmcnt -> staging visible

        f32x4 s[2][4];
#pragma unroll
        for (int a = 0; a < 4; a++) {
            const short8 kf0 = *(const short8*)(Ks + a * 1024 + ka0);
            const short8 kf1 = *(const short8*)(Ks + a * 1024 + ka1);
#pragma unroll
            for (int u = 0; u < 2; u++) {
                s[u][a] = mfma16(kf0, qf[u][0], zz);
                s[u][a] = mfma16(kf1, qf[u][1], s[u][a]);
            }
        }
        union { u32 u[4]; short8 s8; } pu[2][2];
#pragma unroll
        for (int u = 0; u < 2; u++) {
#pragma unroll
            for (int r = 0; r < 4; r++) {
                const float e0 = __builtin_amdgcn_exp2f(s[u][0][r]);
                const float e1 = __builtin_amdgcn_exp2f(s[u][1][r]);
                const float e2 = __builtin_amdgcn_exp2f(s[u][2][r]);
                const float e3 = __builtin_amdgcn_exp2f(s[u][3][r]);
                pu[u][0].u[r] = __builtin_amdgcn_perm(
                    __float_as_uint(e1), __float_as_uint(e0), 0x07060302u);
                pu[u][1].u[r] = __builtin_amdgcn_perm(
                    __float_as_uint(e3), __float_as_uint(e2), 0x07060302u);
            }
            osum[u] = mfma16(ones, pu[u][0].s8, osum[u]);
            osum[u] = mfma16(ones, pu[u][1].s8, osum[u]);
        }
#pragma unroll
        for (int dv = 0; dv < 4; dv++) {
            const short8 vf0 = *(const short8*)(Vs + dv * 1024 + ka0);
            const short8 vf1 = *(const short8*)(Vs + dv * 1024 + ka1);
#pragma unroll
            for (int u = 0; u < 2; u++) {
                o[u][dv] = mfma16(vf0, pu[u][0].s8, o[u][dv]);
                o[u][dv] = mfma16(vf1, pu[u][1].s8, o[u][dv]);
            }
        }
    }

#pragma unroll
    for (int u = 0; u < 2; u++) {
        const float inv = 1.0f / osum[u][0];   // every acc row = denom(q=l16)
        const size_t obase =
            (size_t)(b * S_LEN + q0 + u * 16 + l16) * DM + h * 64 + quad * 4;
#pragma unroll
        for (int d = 0; d < 4; d++) {
            u16x4 pk;
#pragma unroll
            for (int r = 0; r < 4; r++) pk[r] = f2bf(o[u][d][r] * inv);
            *(u16x4*)(O + obase + d * 16) = pk;
        }
    }
}

// ---------------- launch ----------------
extern "C" void kernel_launch(void* const* d_in, const int* in_sizes, int n_in,
                              void* d_out, int out_size, void* d_ws, size_t ws_size,
                              hipStream_t stream) {
    const float* x  = (const float*)d_in[0];
    const float* wq = (const float*)d_in[1];
    const float* bq = (const float*)d_in[2];
    const float* wk = (const float*)d_in[3];
    const float* bk = (const float*)d_in[4];
    const float* wv = (const float*)d_in[5];
    const float* bv = (const float*)d_in[6];
    const float* wo = (const float*)d_in[7];
    const float* bo = (const float*)d_in[8];

    char* ws = (char*)d_ws;
    u16*   wallT   = (u16*)(ws + 64);          // 6 MB
    u16*   woT     = (u16*)(ws + 6291520);     // 2 MB
    float* biasAll = (float*)(ws + 8388672);
    float* biasO   = (float*)(ws + 8400960);
    u16*   xb      = (u16*)(ws + 8405056);     // 8 MB
    u16*   Qb      = (u16*)(ws + 16793664);    // 8 MB
    u16*   Ktg     = (u16*)(ws + 25182272);    // 8 MB (swizzled LDS image)
    u16*   Vtb     = (u16*)(ws + 33570880);    // 8 MB (swizzled LDS image)
    u16*   Obuf    = (u16*)(ws + 41959488);    // 8 MB -> ends 50,348,096

    prep_all<<<3073, 256, 0, stream>>>(x, xb, wq, wk, wv, wo, bq, bk, bv, bo,
                                       wallT, woT, biasAll, biasO);
    gemm_qkv<<<dim3(32, 24), 256, 0, stream>>>(xb, wallT, biasAll,
                                               Qb, Ktg, Vtb, 1024, 3072);
    flash_attn<<<dim3(16, 32), 256, 0, stream>>>(Qb, Ktg, Vtb, Obuf);
    gemm_out64<<<dim3(64, 8), 256, 0, stream>>>(Obuf, woT, biasO,
                                                (float*)d_out, 1024, 1024);
}

// Round 15
// 177.413 us; speedup vs baseline: 1.3503x; 1.0086x over previous
//
#include <hip/hip_runtime.h>

// MultiHeadAttention  B=2, S=2048, DM=1024, H=16, DH=64. f32 in / f32 out.
// R15 = R14 + XCD-aware block swizzle in flash_attn. R14 evidence: flash
// FETCH_SIZE 69.7 MB vs 24 MB working set -> the 16 blocks sharing each
// bh's K/V image were scattered round-robin across the 8 XCDs (x-fastest
// linearization), so every XCD refetched every image from HBM and staging
// loads stalled ~900cyc. Remap: lid = x + 16*y, bh = lid&31, qb = lid>>5
// -> all blocks of bh b have lid == b (mod 8) -> one XCD per bh; 4 images
// (2 MB) per XCD fit its 4 MB L2, staging becomes L2-hit.
// Carried: R10-champion flash body (ones-MFMA denominator), gemm_qkv
// 3 blocks/CU + coalesced epilogue, 64x128 out-proj, fused prep.

#define S_LEN 2048
#define DM 1024
#define MROWS 4096
#define QSCALE 0.1803368801111244f   // 0.125 * log2(e)

typedef unsigned short u16;
typedef unsigned int u32;
typedef __attribute__((ext_vector_type(8))) short short8;
typedef __attribute__((ext_vector_type(4))) float f32x4;
typedef __attribute__((ext_vector_type(4))) unsigned short u16x4;
typedef __attribute__((ext_vector_type(2))) unsigned int u32x2;

__device__ inline u16 f2bf(float f) {
    u32 u = __float_as_uint(f);
    u = u + 0x7fffu + ((u >> 16) & 1u);   // RNE
    return (u16)(u >> 16);
}
__device__ inline void gld_lds16(const u16* g, u16* l) {
    __builtin_amdgcn_global_load_lds(
        (const __attribute__((address_space(1))) void*)g,
        (__attribute__((address_space(3))) void*)l, 16, 0, 0);
}
__device__ inline f32x4 mfma16(short8 a, short8 b, f32x4 c) {
    return __builtin_amdgcn_mfma_f32_16x16x32_bf16(a, b, c, 0, 0, 0);
}

// ---------------- fused: x->bf16 (blocks 0..2047) + weight prep (2048..3072) --
__global__ void prep_all(const float* __restrict__ x, u16* __restrict__ xb,
                         const float* __restrict__ wq, const float* __restrict__ wk,
                         const float* __restrict__ wv, const float* __restrict__ wo,
                         const float* __restrict__ bq, const float* __restrict__ bk,
                         const float* __restrict__ bv, const float* __restrict__ bo,
                         u16* __restrict__ wallT, u16* __restrict__ woT,
                         float* __restrict__ biasAll, float* __restrict__ biasO) {
    const int t = threadIdx.x;
    if (blockIdx.x < 2048) {   // x -> bf16, 8 elems/thread
        const size_t i8 = ((size_t)blockIdx.x * 256 + t) * 8;
        const f32x4 a = ((const f32x4*)x)[i8 / 4];
        const f32x4 b = ((const f32x4*)x)[i8 / 4 + 1];
        u16 o[8];
#pragma unroll
        for (int i = 0; i < 4; i++) { o[i] = f2bf(a[i]); o[4 + i] = f2bf(b[i]); }
        *(short8*)(xb + i8) = *(const short8*)o;
        return;
    }
    const int bid = blockIdx.x - 2048;
    if (bid == 1024) {   // biases
#pragma unroll
        for (int i = 0; i < 4; i++) {
            const int idx = i * 256 + t;
            biasAll[idx]        = bq[idx] * QSCALE;
            biasAll[1024 + idx] = bk[idx];
            biasAll[2048 + idx] = bv[idx];
            biasO[idx]          = bo[idx];
        }
        return;
    }
    __shared__ float lds[64][65];
    const int m  = bid >> 8;
    const int tk = (bid >> 4) & 15;
    const int tn = bid & 15;
    const float* src = (m == 0) ? wq : (m == 1) ? wk : (m == 2) ? wv : wo;
    const float scale = (m == 0) ? QSCALE : 1.0f;
    const int r4 = t >> 6, c = t & 63;
#pragma unroll
    for (int i = 0; i < 16; i++) {
        const int k = tk * 64 + i * 4 + r4;
        lds[i * 4 + r4][c] = src[(size_t)k * 1024 + tn * 64 + c];
    }
    __syncthreads();
#pragma unroll
    for (int i = 0; i < 16; i++) {
        const int n = tn * 64 + i * 4 + r4;
        const int k = tk * 64 + c;
        const u16 v = f2bf(lds[c][i * 4 + r4] * scale);
        if (m < 3) wallT[((size_t)m * 1024 + n) * 1024 + k] = v;
        else       woT[(size_t)n * 1024 + k] = v;
    }
}

// ---------------- QKV GEMM with LDS-staged coalesced epilogue ----------------
// 3 blocks/CU: grid 768 = 256 CUs x 3 -> single residency pass, no tail.
__global__ __launch_bounds__(256, 3)
void gemm_qkv(const u16* __restrict__ A, const u16* __restrict__ Bt,
              const float* __restrict__ bias, u16* __restrict__ Cq,
              u16* __restrict__ Ck, u16* __restrict__ Cv,
              const int K, const int N) {
    __shared__ __align__(16) u16 As[128 * 32];
    __shared__ __align__(16) u16 Bs[128 * 32];
    __shared__ __align__(16) u16 Ct[128 * 136];   // 34 KB epilogue staging
    const int tid = threadIdx.x;
    const int w = tid >> 6, lane = tid & 63;
    const int wm = w >> 1, wn = w & 1;
    const int l16 = lane & 15, quad = lane >> 4;
    const int tm = blockIdx.x * 128;
    const int tn = blockIdx.y * 128;
    const int region = tn >> 10;   // 0=Q, 1=K, 2=V (uniform per block)

    const int sr = w * 16 + (lane >> 2);
    const int sc = (lane & 3) * 8;
    const u16* ag0 = A + (size_t)(tm + sr) * K + sc;
    const u16* ag1 = A + (size_t)(tm + sr + 64) * K + sc;
    const u16* bg0 = Bt + (size_t)(tn + sr) * K + sc;
    const u16* bg1 = Bt + (size_t)(tn + sr + 64) * K + sc;
    u16* al = As + w * 512;
    u16* bl = Bs + w * 512;

    f32x4 acc[4][4];
#pragma unroll
    for (int i = 0; i < 4; i++)
#pragma unroll
        for (int j = 0; j < 4; j++) acc[i][j] = (f32x4){0.f, 0.f, 0.f, 0.f};

    for (int kb = 0; kb < K; kb += 32) {
        __syncthreads();
        gld_lds16(ag0 + kb, al);
        gld_lds16(ag1 + kb, al + 2048);
        gld_lds16(bg0 + kb, bl);
        gld_lds16(bg1 + kb, bl + 2048);
        __syncthreads();
        short8 af[4], bfr[4];
#pragma unroll
        for (int i = 0; i < 4; i++) {
            af[i]  = *(const short8*)(As + (wm * 64 + i * 16 + l16) * 32 + quad * 8);
            bfr[i] = *(const short8*)(Bs + (wn * 64 + i * 16 + l16) * 32 + quad * 8);
        }
#pragma unroll
        for (int i = 0; i < 4; i++)
#pragma unroll
            for (int j = 0; j < 4; j++)
                acc[i][j] = mfma16(af[i], bfr[j], acc[i][j]);
    }

    // ---- stage C into LDS ----
    if (region < 2) {
#pragma unroll
        for (int j = 0; j < 4; j++) {
            const int colL = wn * 64 + j * 16 + l16;
            const float bv = bias[tn + colL];
#pragma unroll
            for (int i = 0; i < 4; i++) {
                const int row0 = wm * 64 + i * 16 + quad * 4;
#pragma unroll
                for (int r = 0; r < 4; r++)
                    Ct[(row0 + r) * 136 + colL] = f2bf(acc[i][j][r] + bv);
            }
        }
    } else {
#pragma unroll
        for (int j = 0; j < 4; j++) {
            const int colL = wn * 64 + j * 16 + l16;
            const float bv = bias[tn + colL];
#pragma unroll
            for (int i = 0; i < 4; i++) {
                const int row0 = wm * 64 + i * 16 + quad * 4;
                u16x4 pk;
#pragma unroll
                for (int r = 0; r < 4; r++) pk[r] = f2bf(acc[i][j][r] + bv);
                *(u16x4*)(Ct + colL * 132 + row0) = pk;
            }
        }
    }
    __syncthreads();

    // ---- coalesced b128 output ----
    if (region == 0) {
#pragma unroll
        for (int p = 0; p < 8; p++) {
            const int rowL = p * 16 + (tid >> 4);
            const int c8 = (tid & 15) * 8;
            const short8 v = *(const short8*)(Ct + rowL * 136 + c8);
            *(short8*)(Cq + (size_t)(tm + rowL) * 1024 + tn + c8) = v;
        }
    } else if (region == 1) {
        const int b = tm >> 11, sBase = tm & 2047;
#pragma unroll
        for (int p = 0; p < 8; p++) {
            const int rowL = p * 16 + (tid >> 4);
            const int c8 = (tid & 15) * 8;
            const short8 v = *(const short8*)(Ct + rowL * 136 + c8);
            const int s = sBase + rowL;
            const int hd = (tn - 1024) + c8;
            const int h = hd >> 6, dd = hd & 63;
            const int chunk = ((dd >> 3) + s) & 7;
            *(short8*)(Ck + (((size_t)(b * 16 + h) * 2048 + s) << 6) + chunk * 8) = v;
        }
    } else {
        const int b = tm >> 11, tBase = (tm & 2047) >> 6;
        const int hBase = (tn >> 6) - 32;
#pragma unroll
        for (int p = 0; p < 8; p++) {
            const int cid = p * 256 + tid;        // 0..2047
            const int q3 = cid & 7;               // phys chunk
            const int colL = (cid >> 3) & 127;
            const int half = cid >> 10;           // s-tile half
            const int d = colL & 63;
            const int h = hBase + (colL >> 6);
            const int c = (q3 - d) & 7;           // logical chunk
            const int base = (c & 3) * 4 + ((c & 4) << 3);
            const u32x2 Ar = *(const u32x2*)(Ct + colL * 132 + half * 64 + base);
            const u32x2 Br = *(const u32x2*)(Ct + colL * 132 + half * 64 + base + 16);
            union { u32 u[4]; short8 s8; } o;
            o.u[0] = __builtin_amdgcn_perm(Br[0], Ar[0], 0x05040100u);
            o.u[1] = __builtin_amdgcn_perm(Br[0], Ar[0], 0x07060302u);
            o.u[2] = __builtin_amdgcn_perm(Br[1], Ar[1], 0x05040100u);
            o.u[3] = __builtin_amdgcn_perm(Br[1], Ar[1], 0x07060302u);
            *(short8*)(Cv + (((size_t)((b * 16 + h) * 32 + tBase + half)) << 12) +
                       d * 64 + q3 * 8) = o.s8;
        }
    }
}

// ---------------- out-proj GEMM: 64x128 tile, f32 out ----------------
__global__ __launch_bounds__(256, 2)
void gemm_out64(const u16* __restrict__ A, const u16* __restrict__ Bt,
                const float* __restrict__ bias, float* __restrict__ C,
                const int K, const int N) {
    __shared__ __align__(16) u16 As[64 * 32];
    __shared__ __align__(16) u16 Bs[128 * 32];
    const int tid = threadIdx.x;
    const int w = tid >> 6, lane = tid & 63;
    const int wm = w >> 1, wn = w & 1;
    const int l16 = lane & 15, quad = lane >> 4;
    const int tm = blockIdx.x * 64;
    const int tn = blockIdx.y * 128;

    const int sr = w * 16 + (lane >> 2);
    const int sc = (lane & 3) * 8;
    const u16* ag  = A + (size_t)(tm + sr) * K + sc;
    const u16* bg0 = Bt + (size_t)(tn + sr) * K + sc;
    const u16* bg1 = Bt + (size_t)(tn + sr + 64) * K + sc;
    u16* al = As + w * 512;
    u16* bl = Bs + w * 512;

    f32x4 acc[2][4];
#pragma unroll
    for (int i = 0; i < 2; i++)
#pragma unroll
        for (int j = 0; j < 4; j++) acc[i][j] = (f32x4){0.f, 0.f, 0.f, 0.f};

    for (int kb = 0; kb < K; kb += 32) {
        __syncthreads();
        gld_lds16(ag + kb, al);
        gld_lds16(bg0 + kb, bl);
        gld_lds16(bg1 + kb, bl + 2048);
        __syncthreads();
        short8 af[2], bfr[4];
#pragma unroll
        for (int i = 0; i < 2; i++)
            af[i] = *(const short8*)(As + (wm * 32 + i * 16 + l16) * 32 + quad * 8);
#pragma unroll
        for (int j = 0; j < 4; j++)
            bfr[j] = *(const short8*)(Bs + (wn * 64 + j * 16 + l16) * 32 + quad * 8);
#pragma unroll
        for (int i = 0; i < 2; i++)
#pragma unroll
            for (int j = 0; j < 4; j++)
                acc[i][j] = mfma16(af[i], bfr[j], acc[i][j]);
    }
#pragma unroll
    for (int j = 0; j < 4; j++) {
        const int col = tn + wn * 64 + j * 16 + l16;
        const float bv = bias[col];
#pragma unroll
        for (int i = 0; i < 2; i++) {
            const int row0 = tm + wm * 32 + i * 16 + quad * 4;
#pragma unroll
            for (int r = 0; r < 4; r++)
                C[(size_t)(row0 + r) * N + col] = acc[i][j][r] + bv;
        }
    }
}

// ---------------- flash attention (R10 body + XCD-aware swizzle) ------------
// lid = x + 16*y; bh = lid&31, qb = lid>>5  =>  all 16 blocks of one bh have
// lid == bh (mod 8) -> same XCD (round-robin dispatch), K/V image L2-resident.
__global__ __launch_bounds__(256, 2)
void flash_attn(const u16* __restrict__ Qb, const u16* __restrict__ Ktg,
                const u16* __restrict__ Vtb, u16* __restrict__ O) {
    __shared__ __align__(16) u16 Ks[4096];
    __shared__ __align__(16) u16 Vs[4096];
    const int tid = threadIdx.x;
    const int w = tid >> 6, lane = tid & 63;
    const int l16 = lane & 15, quad = lane >> 4;
    const int lid = blockIdx.x + blockIdx.y * 16;
    const int bh = lid & 31, b = bh >> 4, h = bh & 15;
    const int q0 = (lid >> 5) * 128 + w * 32;

    short8 qf[2][2];
#pragma unroll
    for (int u = 0; u < 2; u++) {
        const size_t qrow = (size_t)(b * S_LEN + q0 + u * 16 + l16) * 1024 + h * 64;
        qf[u][0] = *(const short8*)(Qb + qrow + quad * 8);
        qf[u][1] = *(const short8*)(Qb + qrow + 32 + quad * 8);
    }
    u16 ones_s[8];
#pragma unroll
    for (int i = 0; i < 8; i++) ones_s[i] = 0x3F80u;   // bf16 1.0
    const short8 ones = *(const short8*)ones_s;

    const u16* kg = Ktg + ((size_t)bh << 17) + w * 1024 + lane * 8;
    const u16* vg = Vtb + ((size_t)bh << 17) + w * 1024 + lane * 8;
    u16* kl = Ks + w * 1024;   // wave-uniform LDS base (+ lane*16B implicit)
    u16* vl = Vs + w * 1024;

    const int ka0 = l16 * 64 + ((quad + l16) & 7) * 8;       // logical chunks 0-3
    const int ka1 = l16 * 64 + ((4 + quad + l16) & 7) * 8;   // logical chunks 4-7

    f32x4 o[2][4], osum[2];
#pragma unroll
    for (int u = 0; u < 2; u++) {
        osum[u] = (f32x4){0.f, 0.f, 0.f, 0.f};
#pragma unroll
        for (int d = 0; d < 4; d++) o[u][d] = (f32x4){0.f, 0.f, 0.f, 0.f};
    }
    const f32x4 zz = (f32x4){0.f, 0.f, 0.f, 0.f};

    for (int t = 0; t < S_LEN / 64; t++) {
        __syncthreads();
        const int off = t * 4096;
        gld_lds16(kg + off,       kl);
        gld_lds16(kg + off + 512, kl + 512);
        gld_lds16(vg + off,       vl);
        gld_lds16(vg + off + 512, vl + 512);
        __syncthreads();   // drains vmcnt -> staging visible

        f32x4 s[2][4];
#pragma unroll
        for (int a = 0; a < 4; a++) {
            const short8 kf0 = *(const short8*)(Ks + a * 1024 + ka0);
            const short8 kf1 = *(const short8*)(Ks + a * 1024 + ka1);
#pragma unroll
            for (int u = 0; u < 2; u++) {
                s[u][a] = mfma16(kf0, qf[u][0], zz);
                s[u][a] = mfma16(kf1, qf[u][1], s[u][a]);
            }
        }
        union { u32 u[4]; short8 s8; } pu[2][2];
#pragma unroll
        for (int u = 0; u < 2; u++) {
#pragma unroll
            for (int r = 0; r < 4; r++) {
                const float e0 = __builtin_amdgcn_exp2f(s[u][0][r]);
                const float e1 = __builtin_amdgcn_exp2f(s[u][1][r]);
                const float e2 = __builtin_amdgcn_exp2f(s[u][2][r]);
                const float e3 = __builtin_amdgcn_exp2f(s[u][3][r]);
                pu[u][0].u[r] = __builtin_amdgcn_perm(
                    __float_as_uint(e1), __float_as_uint(e0), 0x07060302u);
                pu[u][1].u[r] = __builtin_amdgcn_perm(
                    __float_as_uint(e3), __float_as_uint(e2), 0x07060302u);
            }
            osum[u] = mfma16(ones, pu[u][0].s8, osum[u]);
            osum[u] = mfma16(ones, pu[u][1].s8, osum[u]);
        }
#pragma unroll
        for (int dv = 0; dv < 4; dv++) {
            const short8 vf0 = *(const short8*)(Vs + dv * 1024 + ka0);
            const short8 vf1 = *(const short8*)(Vs + dv * 1024 + ka1);
#pragma unroll
            for (int u = 0; u < 2; u++) {
                o[u][dv] = mfma16(vf0, pu[u][0].s8, o[u][dv]);
                o[u][dv] = mfma16(vf1, pu[u][1].s8, o[u][dv]);
            }
        }
    }

#pragma unroll
    for (int u = 0; u < 2; u++) {
        const float inv = 1.0f / osum[u][0];   // every acc row = denom(q=l16)
        const size_t obase =
            (size_t)(b * S_LEN + q0 + u * 16 + l16) * DM + h * 64 + quad * 4;
#pragma unroll
        for (int d = 0; d < 4; d++) {
            u16x4 pk;
#pragma unroll
            for (int r = 0; r < 4; r++) pk[r] = f2bf(o[u][d][r] * inv);
            *(u16x4*)(O + obase + d * 16) = pk;
        }
    }
}

// ---------------- launch ----------------
extern "C" void kernel_launch(void* const* d_in, const int* in_sizes, int n_in,
                              void* d_out, int out_size, void* d_ws, size_t ws_size,
                              hipStream_t stream) {
    const float* x  = (const float*)d_in[0];
    const float* wq = (const float*)d_in[1];
    const float* bq = (const float*)d_in[2];
    const float* wk = (const float*)d_in[3];
    const float* bk = (const float*)d_in[4];
    const float* wv = (const float*)d_in[5];
    const float* bv = (const float*)d_in[6];
    const float* wo = (const float*)d_in[7];
    const float* bo = (const float*)d_in[8];

    char* ws = (char*)d_ws;
    u16*   wallT   = (u16*)(ws + 64);          // 6 MB
    u16*   woT     = (u16*)(ws + 6291520);     // 2 MB
    float* biasAll = (float*)(ws + 8388672);
    float* biasO   = (float*)(ws + 8400960);
    u16*   xb      = (u16*)(ws + 8405056);     // 8 MB
    u16*   Qb      = (u16*)(ws + 16793664);    // 8 MB
    u16*   Ktg     = (u16*)(ws + 25182272);    // 8 MB (swizzled LDS image)
    u16*   Vtb     = (u16*)(ws + 33570880);    // 8 MB (swizzled LDS image)
    u16*   Obuf    = (u16*)(ws + 41959488);    // 8 MB -> ends 50,348,096

    prep_all<<<3073, 256, 0, stream>>>(x, xb, wq, wk, wv, wo, bq, bk, bv, bo,
                                       wallT, woT, biasAll, biasO);
    gemm_qkv<<<dim3(32, 24), 256, 0, stream>>>(xb, wallT, biasAll,
                                               Qb, Ktg, Vtb, 1024, 3072);
    flash_attn<<<dim3(16, 32), 256, 0, stream>>>(Qb, Ktg, Vtb, Obuf);
    gemm_out64<<<dim3(64, 8), 256, 0, stream>>>(Obuf, woT, biasO,
                                                (float*)d_out, 1024, 1024);
}